// Round 9
// baseline (95.980 us; speedup 1.0000x reference)
//
#include <hip/hip_runtime.h>
#include <hip/hip_bf16.h>

// BatchIrregularDownsample2d (D=2): out[b,c,j] = in[b,c,G[b,j]]
// R9: no-LDS fused row kernel — tail gathers directly from global (sorted
// indices share cache lines; L1/L2 dedup), no barrier, no phase serialization.
// NT stores throughout; build_idx v2 (coalesced flags + shuffle scan) kept.

#define HW_FULL 65536
#define SUBN   16384
#define T1     1024
#define PER_T  16
#define TB     512

typedef float f4a __attribute__((ext_vector_type(4), aligned(4)));
typedef float f4v __attribute__((ext_vector_type(4)));
typedef int   i4a __attribute__((ext_vector_type(4), aligned(4)));

__global__ __launch_bounds__(1024) void build_idx_kernel(
    const int* __restrict__ mask, int* __restrict__ hdr, int* __restrict__ gt, int M)
{
    const int b = blockIdx.x;
    const int t = threadIdx.x;
    const int* mb = mask + (long long)b * HW_FULL;

    __shared__ unsigned char flags[SUBN];
    __shared__ unsigned long long wsum[16];

    // Coalesced flag pass: entry e = k*1024 + t (lanes contiguous in subgrid)
    #pragma unroll
    for (int k = 0; k < 16; ++k) {
        int e = (k << 10) + t;
        int r = e >> 7;
        int c = e & 127;
        int m = mb[(r << 9) + (c << 1)];
        int z  = (m == 0);
        int cs = (m >= 1);
        int dt = (m == 1);
        int tl = ((r | c) & 1) == 0;
        int kl = (tl && (m >= 2)) ? 1 : 0;
        flags[e] = (unsigned char)(z | (cs << 1) | (dt << 2) | (kl << 3));
    }
    __syncthreads();

    // Per-thread contiguous segment (row-major order preserved)
    unsigned char fl[PER_T];
    unsigned long long local = 0ULL;
    #pragma unroll
    for (int k = 0; k < PER_T; ++k) {
        unsigned char f = flags[t * PER_T + k];
        fl[k] = f;
        local += (unsigned long long)(f & 1)
               | ((unsigned long long)((f >> 1) & 1) << 16)
               | ((unsigned long long)((f >> 2) & 1) << 32)
               | ((unsigned long long)((f >> 3) & 1) << 48);
    }

    // Wave-level inclusive scan, then cross-wave scan
    unsigned long long v = local;
    #pragma unroll
    for (int off = 1; off < 64; off <<= 1) {
        unsigned long long n = __shfl_up(v, off, 64);
        if ((t & 63) >= off) v += n;
    }
    if ((t & 63) == 63) wsum[t >> 6] = v;
    __syncthreads();
    if (t < 16) {
        unsigned long long w = wsum[t];
        #pragma unroll
        for (int off = 1; off < 16; off <<= 1) {
            unsigned long long n = __shfl_up(w, off, 16);
            if (t >= off) w += n;
        }
        wsum[t] = w;   // inclusive wave totals
    }
    __syncthreads();

    unsigned long long waveoff = (t >= 64) ? wsum[(t >> 6) - 1] : 0ULL;
    unsigned long long incl = v + waveoff;
    unsigned long long tot  = wsum[15];
    unsigned long long ex   = incl - local;

    const int zt    = (int)( tot        & 0xFFFF);
    const int cst   = (int)((tot >> 16) & 0xFFFF);
    const int ndt   = (int)((tot >> 32) & 0xFFFF);
    const int nkl   = (int)((tot >> 48) & 0xFFFF);
    const int start = zt * 4;

    int csP = (int)((ex >> 16) & 0xFFFF);
    int dtP = (int)((ex >> 32) & 0xFFFF);
    int klP = (int)((ex >> 48) & 0xFFFF);

    int* gtb = gt + (long long)b * M;
    #pragma unroll
    for (int k = 0; k < PER_T; ++k) {
        int f = fl[k];
        if (f & 4) { gtb[dtP]       = start + csP; ++dtP; }
        if (f & 8) { gtb[ndt + klP] = start + csP; ++klP; }
        if (f & 2) { ++csP; }
    }

    if (t == 0) {
        hdr[b * 4 + 0] = start;
        hdr[b * 4 + 1] = cst;                 // cs region size
        hdr[b * 4 + 2] = ndt + nkl;           // ntail
        hdr[b * 4 + 3] = start + ndt + nkl;   // len
    }
}

__global__ __launch_bounds__(TB) void fused_row_kernel(
    const float* __restrict__ in, const int* __restrict__ hdr,
    const int* __restrict__ gt, float* __restrict__ out,
    int N, int M, int cshift)
{
    const int row   = blockIdx.x;
    const int b     = row >> cshift;
    const int start = hdr[b * 4 + 0];     // multiple of 4
    const int ntail = hdr[b * 4 + 2];
    const long long rowM = (long long)row * M;
    const long long rowN = (long long)row * N;
    const int tid = threadIdx.x;

    const float* rin  = in  + rowN;       // 16B aligned (N%4==0)
    const int*   gtb  = gt + (long long)b * M;
    float*       rout = out + rowM;

    // ---- Prefix copy j in [0, start) ----
    const int h  = (int)((4 - (rowM & 3)) & 3);          // output-quad head
    const int nq = (start >= h) ? ((start - h) >> 2) : 0;
    for (int k = tid; k < nq; k += TB) {
        const int j = h + (k << 2);
        f4a lv = *reinterpret_cast<const f4a*>(rin + j);
        f4v v; v.x = lv.x; v.y = lv.y; v.z = lv.z; v.w = lv.w;
        __builtin_nontemporal_store(v, reinterpret_cast<f4v*>(rout + j));
    }
    if (tid == 0) {
        const int hh = (h < start) ? h : start;
        for (int j = 0; j < hh; ++j)
            __builtin_nontemporal_store(rin[j], rout + j);
        if (start >= h) {
            for (int j = h + (nq << 2); j < start; ++j)
                __builtin_nontemporal_store(rin[j], rout + j);
        }
    }

    // ---- Tail gather j in [start, M): direct global gather ----
    const int span = M - start;
    const int h2   = (h < span) ? h : span;     // (rowM+start)%4 == rowM%4
    const int nq2  = (span >= h) ? ((span - h) >> 2) : 0;

    for (int k = tid; k < nq2; k += TB) {
        const int t = h + (k << 2);             // tail-relative
        i4a g = *reinterpret_cast<const i4a*>(gtb + t);
        // clamp indices in the zero-pad region before loading (gt is
        // unwritten there); select zero after.
        const int g0 = (t + 0 < ntail) ? g.x : 0;
        const int g1 = (t + 1 < ntail) ? g.y : 0;
        const int g2 = (t + 2 < ntail) ? g.z : 0;
        const int g3 = (t + 3 < ntail) ? g.w : 0;
        f4v v;
        v.x = (t + 0 < ntail) ? rin[g0] : 0.0f;
        v.y = (t + 1 < ntail) ? rin[g1] : 0.0f;
        v.z = (t + 2 < ntail) ? rin[g2] : 0.0f;
        v.w = (t + 3 < ntail) ? rin[g3] : 0.0f;
        __builtin_nontemporal_store(v, reinterpret_cast<f4v*>(rout + start + t));
    }
    if (tid == TB - 1) {
        for (int t = 0; t < h2; ++t) {          // head dwords
            float x = (t < ntail) ? rin[gtb[t]] : 0.0f;
            __builtin_nontemporal_store(x, rout + start + t);
        }
        if (span >= h) {                        // trailing rem dwords
            for (int t = h + (nq2 << 2); t < span; ++t) {
                float x = (t < ntail) ? rin[gtb[t]] : 0.0f;
                __builtin_nontemporal_store(x, rout + start + t);
            }
        }
    }
}

extern "C" void kernel_launch(void* const* d_in, const int* in_sizes, int n_in,
                              void* d_out, int out_size, void* d_ws, size_t ws_size,
                              hipStream_t stream) {
    const float* x    = (const float*)d_in[0];
    const int*   mask = (const int*)d_in[1];
    float*       out  = (float*)d_out;

    const int B = in_sizes[1] / HW_FULL;          // 8
    const int C = 256;
    const int N = in_sizes[0] / (B * C);          // 32776
    const int M = out_size   / (B * C);           // 28681
    const int nrows = B * C;                      // 2048

    int cshift = 0;
    while ((1 << cshift) < C) ++cshift;

    int* hdr = (int*)d_ws;                        // B*4 ints
    int* gt  = hdr + 32;                          // B*M ints

    build_idx_kernel<<<B, T1, 0, stream>>>(mask, hdr, gt, M);
    fused_row_kernel<<<nrows, TB, 0, stream>>>(x, hdr, gt, out, N, M, cshift);
}

// Round 10
// 91.254 us; speedup vs baseline: 1.0518x; 1.0518x over previous
//
#include <hip/hip_runtime.h>
#include <hip/hip_bf16.h>

// BatchIrregularDownsample2d (D=2): out[b,c,j] = in[b,c,G[b,j]]
// R10 = R8 structure (LDS-staged tail, T14 stage-split, NT stores,
// build_idx v2) with TB=1024: 2 blocks/CU x 16 waves = 100% occupancy
// (R8 was 57% at TB=512). Clean occupancy A/B on the winning structure.

#define HW_FULL 65536
#define SUBN   16384
#define T1     1024
#define PER_T  16
#define CS_CAP 11264   // max staged cs dwords (44 KB LDS)
#define TB     1024
#define STI    3       // staging iterations: ceil((CS_CAP/4)/TB)

typedef float f4a __attribute__((ext_vector_type(4), aligned(4)));
typedef float f4v __attribute__((ext_vector_type(4)));
typedef int   i4a __attribute__((ext_vector_type(4), aligned(4)));

__global__ __launch_bounds__(1024) void build_idx_kernel(
    const int* __restrict__ mask, int* __restrict__ hdr, int* __restrict__ gt, int M)
{
    const int b = blockIdx.x;
    const int t = threadIdx.x;
    const int* mb = mask + (long long)b * HW_FULL;

    __shared__ unsigned char flags[SUBN];
    __shared__ unsigned long long wsum[16];

    // Coalesced flag pass: entry e = k*1024 + t (lanes contiguous in subgrid)
    #pragma unroll
    for (int k = 0; k < 16; ++k) {
        int e = (k << 10) + t;
        int r = e >> 7;
        int c = e & 127;
        int m = mb[(r << 9) + (c << 1)];
        int z  = (m == 0);
        int cs = (m >= 1);
        int dt = (m == 1);
        int tl = ((r | c) & 1) == 0;
        int kl = (tl && (m >= 2)) ? 1 : 0;
        flags[e] = (unsigned char)(z | (cs << 1) | (dt << 2) | (kl << 3));
    }
    __syncthreads();

    // Per-thread contiguous segment (row-major order preserved)
    unsigned char fl[PER_T];
    unsigned long long local = 0ULL;
    #pragma unroll
    for (int k = 0; k < PER_T; ++k) {
        unsigned char f = flags[t * PER_T + k];
        fl[k] = f;
        local += (unsigned long long)(f & 1)
               | ((unsigned long long)((f >> 1) & 1) << 16)
               | ((unsigned long long)((f >> 2) & 1) << 32)
               | ((unsigned long long)((f >> 3) & 1) << 48);
    }

    // Wave-level inclusive scan, then cross-wave scan
    unsigned long long v = local;
    #pragma unroll
    for (int off = 1; off < 64; off <<= 1) {
        unsigned long long n = __shfl_up(v, off, 64);
        if ((t & 63) >= off) v += n;
    }
    if ((t & 63) == 63) wsum[t >> 6] = v;
    __syncthreads();
    if (t < 16) {
        unsigned long long w = wsum[t];
        #pragma unroll
        for (int off = 1; off < 16; off <<= 1) {
            unsigned long long n = __shfl_up(w, off, 16);
            if (t >= off) w += n;
        }
        wsum[t] = w;   // inclusive wave totals
    }
    __syncthreads();

    unsigned long long waveoff = (t >= 64) ? wsum[(t >> 6) - 1] : 0ULL;
    unsigned long long incl = v + waveoff;
    unsigned long long tot  = wsum[15];
    unsigned long long ex   = incl - local;

    const int zt    = (int)( tot        & 0xFFFF);
    const int cst   = (int)((tot >> 16) & 0xFFFF);
    const int ndt   = (int)((tot >> 32) & 0xFFFF);
    const int nkl   = (int)((tot >> 48) & 0xFFFF);
    const int start = zt * 4;

    int csP = (int)((ex >> 16) & 0xFFFF);
    int dtP = (int)((ex >> 32) & 0xFFFF);
    int klP = (int)((ex >> 48) & 0xFFFF);

    int* gtb = gt + (long long)b * M;
    #pragma unroll
    for (int k = 0; k < PER_T; ++k) {
        int f = fl[k];
        if (f & 4) { gtb[dtP]       = start + csP; ++dtP; }
        if (f & 8) { gtb[ndt + klP] = start + csP; ++klP; }
        if (f & 2) { ++csP; }
    }

    if (t == 0) {
        hdr[b * 4 + 0] = start;
        hdr[b * 4 + 1] = cst;                 // cs region size
        hdr[b * 4 + 2] = ndt + nkl;           // ntail
        hdr[b * 4 + 3] = start + ndt + nkl;   // len
    }
}

__global__ __launch_bounds__(TB) void fused_row_kernel(
    const float* __restrict__ in, const int* __restrict__ hdr,
    const int* __restrict__ gt, float* __restrict__ out,
    int N, int M, int cshift)
{
    const int row   = blockIdx.x;
    const int b     = row >> cshift;
    const int start = hdr[b * 4 + 0];     // multiple of 4
    const int csn   = hdr[b * 4 + 1];
    const int ntail = hdr[b * 4 + 2];
    const long long rowM = (long long)row * M;
    const long long rowN = (long long)row * N;
    const int tid = threadIdx.x;

    const float* rin  = in  + rowN;       // 16B aligned (N%4==0)
    const float* src  = rin + start;      // 16B aligned (start%4==0)
    const int*   gtb  = gt + (long long)b * M;
    float*       rout = out + rowM;

    __shared__ __align__(16) float lds[CS_CAP];
    const bool staged = (csn <= CS_CAP);
    const int  cs4    = csn & ~3;

    // ---- Phase A1: ISSUE staging loads into registers (T14 split) ----
    f4a sreg[STI];
    if (staged) {
        #pragma unroll
        for (int it = 0; it < STI; ++it) {
            const int i = (tid << 2) + it * (TB << 2);
            if (i < cs4) sreg[it] = *reinterpret_cast<const f4a*>(src + i);
        }
    }

    // ---- Phase B: prefix copy j in [0, start) — hides staging latency ----
    const int h  = (int)((4 - (rowM & 3)) & 3);          // output-quad head
    const int nq = (start >= h) ? ((start - h) >> 2) : 0;
    for (int k = tid; k < nq; k += TB) {
        const int j = h + (k << 2);
        f4a lv = *reinterpret_cast<const f4a*>(rin + j);
        f4v v; v.x = lv.x; v.y = lv.y; v.z = lv.z; v.w = lv.w;
        __builtin_nontemporal_store(v, reinterpret_cast<f4v*>(rout + j));
    }
    if (tid == 0) {
        const int hh = (h < start) ? h : start;
        for (int j = 0; j < hh; ++j)
            __builtin_nontemporal_store(rin[j], rout + j);
        if (start >= h) {
            for (int j = h + (nq << 2); j < start; ++j)
                __builtin_nontemporal_store(rin[j], rout + j);
        }
    }

    // ---- Phase A2: LDS writes (loads have had B's duration to land) ----
    if (staged) {
        #pragma unroll
        for (int it = 0; it < STI; ++it) {
            const int i = (tid << 2) + it * (TB << 2);
            if (i < cs4) {
                f4v v; v.x = sreg[it].x; v.y = sreg[it].y;
                       v.z = sreg[it].z; v.w = sreg[it].w;
                *reinterpret_cast<f4v*>(&lds[i]) = v;
            }
        }
        if (tid < (csn & 3)) lds[cs4 + tid] = src[cs4 + tid];
    }

    __syncthreads();

    // ---- Phase C: tail gather j in [start, M) from LDS ----
    const int span = M - start;
    const int h2   = (h < span) ? h : span;     // (rowM+start)%4 == rowM%4
    const int nq2  = (span >= h) ? ((span - h) >> 2) : 0;

    for (int k = tid; k < nq2; k += TB) {
        const int t = h + (k << 2);             // tail-relative
        i4a g = *reinterpret_cast<const i4a*>(gtb + t);
        f4v v;
        v.x = (t + 0 < ntail) ? (staged ? lds[g.x - start] : rin[g.x]) : 0.0f;
        v.y = (t + 1 < ntail) ? (staged ? lds[g.y - start] : rin[g.y]) : 0.0f;
        v.z = (t + 2 < ntail) ? (staged ? lds[g.z - start] : rin[g.z]) : 0.0f;
        v.w = (t + 3 < ntail) ? (staged ? lds[g.w - start] : rin[g.w]) : 0.0f;
        __builtin_nontemporal_store(v, reinterpret_cast<f4v*>(rout + start + t));
    }
    if (tid == TB - 1) {
        for (int t = 0; t < h2; ++t) {          // head dwords
            float x = (t < ntail) ? (staged ? lds[gtb[t] - start] : rin[gtb[t]]) : 0.0f;
            __builtin_nontemporal_store(x, rout + start + t);
        }
        if (span >= h) {                        // trailing rem dwords
            for (int t = h + (nq2 << 2); t < span; ++t) {
                float x = (t < ntail) ? (staged ? lds[gtb[t] - start] : rin[gtb[t]]) : 0.0f;
                __builtin_nontemporal_store(x, rout + start + t);
            }
        }
    }
}

extern "C" void kernel_launch(void* const* d_in, const int* in_sizes, int n_in,
                              void* d_out, int out_size, void* d_ws, size_t ws_size,
                              hipStream_t stream) {
    const float* x    = (const float*)d_in[0];
    const int*   mask = (const int*)d_in[1];
    float*       out  = (float*)d_out;

    const int B = in_sizes[1] / HW_FULL;          // 8
    const int C = 256;
    const int N = in_sizes[0] / (B * C);          // 32776
    const int M = out_size   / (B * C);           // 28681
    const int nrows = B * C;                      // 2048

    int cshift = 0;
    while ((1 << cshift) < C) ++cshift;

    int* hdr = (int*)d_ws;                        // B*4 ints
    int* gt  = hdr + 32;                          // B*M ints

    build_idx_kernel<<<B, T1, 0, stream>>>(mask, hdr, gt, M);
    fused_row_kernel<<<nrows, TB, 0, stream>>>(x, hdr, gt, out, N, M, cshift);
}